// Round 6
// baseline (3459.267 us; speedup 1.0000x reference)
//
#include <hip/hip_runtime.h>
#include <stdint.h>

#define S_LEN 2048
#define D_DIM 1024
#define NHEAD 16
#define HD    64
#define TOPK  409   // max(1, int(2048*(1.0-0.8)))

typedef unsigned short u16;
typedef __attribute__((ext_vector_type(8))) short bf16x8;
typedef __attribute__((ext_vector_type(4))) float f32x4;
#define MFMA __builtin_amdgcn_mfma_f32_16x16x32_bf16

__device__ __forceinline__ u16 f2b(float f) {                // fp32 -> bf16 RNE
    unsigned u = __float_as_uint(f);
    return (u16)((u + 0x7fffu + ((u >> 16) & 1u)) >> 16);
}
__device__ __forceinline__ float b2f(u16 h) {
    return __uint_as_float(((unsigned)h) << 16);
}

// ---------------------------------------------------------------------------
// fp32 -> bf16 hi/lo split (hi+lo reproduces fp32 to ~2^-16 rel)
// ---------------------------------------------------------------------------
__global__ __launch_bounds__(256, 4)
void split_f32(const float* __restrict__ src, u16* __restrict__ hi,
               u16* __restrict__ lo, int n4)
{
    const int i = blockIdx.x * 256 + threadIdx.x;
    if (i >= n4) return;
    const float4 v = ((const float4*)src)[i];
    const float vv[4] = {v.x, v.y, v.z, v.w};
    u16 h4[4], l4[4];
#pragma unroll
    for (int c = 0; c < 4; ++c) {
        h4[c] = f2b(vv[c]);
        l4[c] = f2b(vv[c] - b2f(h4[c]));
    }
    ((ushort4*)hi)[i] = make_ushort4(h4[0], h4[1], h4[2], h4[3]);
    ((ushort4*)lo)[i] = make_ushort4(l4[0], l4[1], l4[2], l4[3]);
}

// ---------------------------------------------------------------------------
__global__ __launch_bounds__(256, 4)
void zero_f32(float* __restrict__ p, int n4)
{
    const int i = blockIdx.x * 256 + threadIdx.x;
    if (i < n4) ((float4*)p)[i] = make_float4(0.f, 0.f, 0.f, 0.f);
}

// ---------------------------------------------------------------------------
// Projection GEMM via 3x bf16-split MFMA: Out = A @ W^T + bias.
// A: [M x 1024] (hi/lo bf16), W: [1024 x 1024] row-major k-contig (hi/lo).
// Block 512 thr = 8 waves; block tile 128x128; wave tile 64(m) x 32(n).
// MODE 0: Q/K -> o1/o2 hi/lo bf16 in [b,h,s,e]. MODE 1: V -> o1 bf16 in
// [b,h,e,s] (pre-transposed for PV). MODE 2: fp32 out[m][n].
// ---------------------------------------------------------------------------
template<int MODE>
__global__ __launch_bounds__(512, 2)
void proj_mfma(const u16* __restrict__ Ahi, const u16* __restrict__ Alo,
               const u16* __restrict__ Whi, const u16* __restrict__ Wlo,
               const float* __restrict__ bias, float* __restrict__ outf,
               u16* __restrict__ o1, u16* __restrict__ o2)
{
    const int t = threadIdx.x, w = t >> 6, l = t & 63;
    const int lq = l & 15, quad = l >> 4;
    const int m0 = blockIdx.y * 128 + (w >> 2) * 64;
    const int n0 = blockIdx.x * 128 + (w & 3) * 32;

    f32x4 acc[4][2];
#pragma unroll
    for (int i = 0; i < 4; ++i)
#pragma unroll
        for (int j = 0; j < 2; ++j) acc[i][j] = (f32x4){0.f, 0.f, 0.f, 0.f};

    const size_t abase = (size_t)(m0 + lq) * D_DIM + quad * 8;
    const size_t bbase = (size_t)(n0 + lq) * D_DIM + quad * 8;

#pragma unroll 2
    for (int k0 = 0; k0 < D_DIM; k0 += 32) {
        bf16x8 ah[4], al[4], bh[2], bl[2];
#pragma unroll
        for (int i = 0; i < 4; ++i) {
            ah[i] = *(const bf16x8*)(Ahi + abase + (size_t)i * 16 * D_DIM + k0);
            al[i] = *(const bf16x8*)(Alo + abase + (size_t)i * 16 * D_DIM + k0);
        }
#pragma unroll
        for (int j = 0; j < 2; ++j) {
            bh[j] = *(const bf16x8*)(Whi + bbase + (size_t)j * 16 * D_DIM + k0);
            bl[j] = *(const bf16x8*)(Wlo + bbase + (size_t)j * 16 * D_DIM + k0);
        }
#pragma unroll
        for (int i = 0; i < 4; ++i)
#pragma unroll
            for (int j = 0; j < 2; ++j) {
                acc[i][j] = MFMA(ah[i], bh[j], acc[i][j], 0, 0, 0);
                acc[i][j] = MFMA(ah[i], bl[j], acc[i][j], 0, 0, 0);
                acc[i][j] = MFMA(al[i], bh[j], acc[i][j], 0, 0, 0);
            }
    }

#pragma unroll
    for (int j = 0; j < 2; ++j) {
        const int n = n0 + j * 16 + lq;
        const float bb = bias[n];
        const int hh = n >> 6, ee = n & 63;
#pragma unroll
        for (int i = 0; i < 4; ++i) {
            const int mb = m0 + i * 16 + quad * 4;
            const int bbm = mb >> 11, ss = mb & 2047;
            if (MODE == 2) {
#pragma unroll
                for (int r = 0; r < 4; ++r)
                    outf[(size_t)(mb + r) * D_DIM + n] = acc[i][j][r] + bb;
            } else if (MODE == 1) {
                ushort4 pk;
                pk.x = f2b(acc[i][j][0] + bb);
                pk.y = f2b(acc[i][j][1] + bb);
                pk.z = f2b(acc[i][j][2] + bb);
                pk.w = f2b(acc[i][j][3] + bb);
                *(ushort4*)(o1 + ((size_t)((bbm * NHEAD + hh) * HD + ee)) * S_LEN + ss) = pk;
            } else {
#pragma unroll
                for (int r = 0; r < 4; ++r) {
                    const float v = acc[i][j][r] + bb;
                    const size_t idx = ((size_t)(bbm * NHEAD + hh) * S_LEN + ss + r) * HD + ee;
                    const u16 h = f2b(v);
                    o1[idx] = h;
                    o2[idx] = f2b(v - b2f(h));
                }
            }
        }
    }
}

// ---------------------------------------------------------------------------
// Attention: block = 512 thr (8 waves) owns (b, 16 q-rows) and EIGHT heads
// (blockIdx.y selects heads 0-7 or 8-15) -> 512 blocks, TWO per CU.
// Score phase restructured into THREE passes (qh*Khi, qh*Klo, ql*Khi) so the
// peak live set stays under the 128-reg cap (acc 64 + 2 q frags + unroll-2
// K in flight + addrs ~= 105): same MFMA accumulation order per element ->
// bit-identical scores, at 1.5x K reads (L2-resident). avg accumulated per
// head directly into global via atomicAdd (verified R5). Top-k threshold:
// mu/sigma-seeded bisection COUNT select: round 0 on z-grid, 5 quadrisection
// rounds -> threshold within ~6e-5 of exact kth. Softmax fp32, PV bf16 MFMA
// via LDS-staged attn, HO written bf16 hi/lo. avg pre-zeroed by zero_f32.
// ---------------------------------------------------------------------------
__global__ __launch_bounds__(512, 4)
void attn_mfma(const u16* __restrict__ Qhi, const u16* __restrict__ Qlo,
               const u16* __restrict__ Khi, const u16* __restrict__ Klo,
               const u16* __restrict__ Vt,  const float* __restrict__ temp,
               u16* __restrict__ HOhi, u16* __restrict__ HOlo,
               float* __restrict__ avg)
{
    __shared__ __align__(16) u16 aLds[16 * 2056];  // attn bf16, stride 2056
    __shared__ float pvpart[4 * 16 * 16];          // PV j-half partials
    __shared__ int   cnts[16][8][5];               // per-row per-wave counts
    __shared__ float red[16][8][2];                // mu/var (and Z) partials
    __shared__ float rowMu[16], rowSig[16], rowLo[16], rowHi[16], rowZi[16];

    const int t = threadIdx.x, w = t >> 6, l = t & 63;
    const int lq = l & 15, quad = l >> 4;
    const int b  = blockIdx.x >> 7;
    const int q0 = (blockIdx.x & 127) << 4;
    const int h0 = blockIdx.y << 3;                // head-half base

#pragma unroll 1
    for (int hh = 0; hh < 8; ++hh) {
        const int h = h0 + hh;
        const size_t bh = (size_t)(b * NHEAD + h) * S_LEN;
        const float tscale = 0.125f / fmaxf(temp[h], 0.1f);

        const u16* qph = Qhi + (bh + q0 + lq) * HD + quad * 8;
        const u16* qpl = Qlo + (bh + q0 + lq) * HD + quad * 8;
        const size_t koff = (bh + w * 256 + lq) * HD + quad * 8;

        // ---- scores: 3 passes, each with only 2 q frags live ---------------
        f32x4 acc[16];
#pragma unroll
        for (int tt = 0; tt < 16; ++tt) acc[tt] = (f32x4){0.f, 0.f, 0.f, 0.f};

        {   // pass 1: qh . Khi
            const bf16x8 qh0 = *(const bf16x8*)qph;
            const bf16x8 qh1 = *(const bf16x8*)(qph + 32);
            const u16* kp = Khi + koff;
#pragma unroll 2
            for (int tt = 0; tt < 16; ++tt) {
                const bf16x8 k0 = *(const bf16x8*)(kp + tt * 16 * HD);
                const bf16x8 k1 = *(const bf16x8*)(kp + tt * 16 * HD + 32);
                acc[tt] = MFMA(qh0, k0, acc[tt], 0, 0, 0);
                acc[tt] = MFMA(qh1, k1, acc[tt], 0, 0, 0);
            }
        }
        {   // pass 2: qh . Klo
            const bf16x8 qh0 = *(const bf16x8*)qph;
            const bf16x8 qh1 = *(const bf16x8*)(qph + 32);
            const u16* kp = Klo + koff;
#pragma unroll 2
            for (int tt = 0; tt < 16; ++tt) {
                const bf16x8 m0 = *(const bf16x8*)(kp + tt * 16 * HD);
                const bf16x8 m1 = *(const bf16x8*)(kp + tt * 16 * HD + 32);
                acc[tt] = MFMA(qh0, m0, acc[tt], 0, 0, 0);
                acc[tt] = MFMA(qh1, m1, acc[tt], 0, 0, 0);
            }
        }
        {   // pass 3: ql . Khi
            const bf16x8 ql0 = *(const bf16x8*)qpl;
            const bf16x8 ql1 = *(const bf16x8*)(qpl + 32);
            const u16* kp = Khi + koff;
#pragma unroll 2
            for (int tt = 0; tt < 16; ++tt) {
                const bf16x8 k0 = *(const bf16x8*)(kp + tt * 16 * HD);
                const bf16x8 k1 = *(const bf16x8*)(kp + tt * 16 * HD + 32);
                acc[tt] = MFMA(ql0, k0, acc[tt], 0, 0, 0);
                acc[tt] = MFMA(ql1, k1, acc[tt], 0, 0, 0);
            }
        }
#pragma unroll
        for (int tt = 0; tt < 16; ++tt) acc[tt] *= tscale;

        __syncthreads();   // B0: prev head fully done with LDS

        // ---- per-row mean / sigma ------------------------------------------
        {
#pragma unroll
            for (int r = 0; r < 4; ++r) {
                float s1 = 0.f, s2 = 0.f;
#pragma unroll
                for (int tt = 0; tt < 16; ++tt) {
                    const float v = acc[tt][r];
                    s1 += v;
                    s2 = __fmaf_rn(v, v, s2);
                }
#pragma unroll
                for (int off = 1; off < 16; off <<= 1) {
                    s1 += __shfl_xor(s1, off, 16);
                    s2 += __shfl_xor(s2, off, 16);
                }
                if (lq == 0) {
                    red[quad * 4 + r][w][0] = s1;
                    red[quad * 4 + r][w][1] = s2;
                }
            }
        }
        __syncthreads();   // B1
        if (t < 16) {
            float a = 0.f, c = 0.f;
#pragma unroll
            for (int ww = 0; ww < 8; ++ww) { a += red[t][ww][0]; c += red[t][ww][1]; }
            const float mu = a * (1.f / 2048.f);
            const float va = c * (1.f / 2048.f) - mu * mu;
            rowMu[t] = mu;
            rowSig[t] = sqrtf(fmaxf(va, 0.f));
        }
        __syncthreads();   // B2

        // ---- round 0: z-grid {0.55..1.15} + out-of-bracket fallback --------
        {
#pragma unroll
            for (int r = 0; r < 4; ++r) {
                const float mu = rowMu[quad * 4 + r], sg = rowSig[quad * 4 + r];
                float th[5];
                int c[5];
#pragma unroll
                for (int i = 0; i < 5; ++i) {
                    th[i] = __fmaf_rn(sg, 0.55f + 0.15f * (float)i, mu);
                    c[i] = 0;
                }
#pragma unroll
                for (int tt = 0; tt < 16; ++tt) {
                    const float v = acc[tt][r];
#pragma unroll
                    for (int i = 0; i < 5; ++i) c[i] += (v >= th[i]) ? 1 : 0;
                }
#pragma unroll
                for (int off = 1; off < 16; off <<= 1)
#pragma unroll
                    for (int i = 0; i < 5; ++i) c[i] += __shfl_xor(c[i], off, 16);
                if (lq == 0)
#pragma unroll
                    for (int i = 0; i < 5; ++i) cnts[quad * 4 + r][w][i] = c[i];
            }
        }
        __syncthreads();   // B3
        if (t < 16) {
            int c[5] = {0, 0, 0, 0, 0};
#pragma unroll
            for (int ww = 0; ww < 8; ++ww)
#pragma unroll
                for (int i = 0; i < 5; ++i) c[i] += cnts[t][ww][i];
            const float mu = rowMu[t], sg = rowSig[t];
            float lo, hi;
            if (c[0] < TOPK) {
                lo = __fmaf_rn(sg, -6.f, mu);
                hi = __fmaf_rn(sg, 0.55f + 0.15f * 0.f, mu);
            } else if (c[4] >= TOPK) {
                lo = __fmaf_rn(sg, 0.55f + 0.15f * 4.f, mu);
                hi = __fmaf_rn(sg, 6.f, mu);
            } else {
                int bi = 0;
#pragma unroll
                for (int j = 1; j < 4; ++j) if (c[j] >= TOPK) bi = j;
                lo = __fmaf_rn(sg, 0.55f + 0.15f * (float)bi, mu);
                hi = __fmaf_rn(sg, 0.55f + 0.15f * (float)(bi + 1), mu);
            }
            rowLo[t] = lo;
            rowHi[t] = hi;
        }
        __syncthreads();   // B4

        // ---- 5 quadrisection refine rounds ---------------------------------
#pragma unroll 1
        for (int rd = 0; rd < 5; ++rd) {
            {
#pragma unroll
                for (int r = 0; r < 4; ++r) {
                    const float lo_ = rowLo[quad * 4 + r], hi_ = rowHi[quad * 4 + r];
                    const float w4 = __fmul_rn(__fsub_rn(hi_, lo_), 0.25f);
                    float th[3];
                    int c[3];
#pragma unroll
                    for (int j = 0; j < 3; ++j) {
                        th[j] = __fmaf_rn(w4, (float)(j + 1), lo_);
                        c[j] = 0;
                    }
#pragma unroll
                    for (int tt = 0; tt < 16; ++tt) {
                        const float v = acc[tt][r];
#pragma unroll
                        for (int j = 0; j < 3; ++j) c[j] += (v >= th[j]) ? 1 : 0;
                    }
#pragma unroll
                    for (int off = 1; off < 16; off <<= 1)
#pragma unroll
                        for (int j = 0; j < 3; ++j) c[j] += __shfl_xor(c[j], off, 16);
                    if (lq == 0)
#pragma unroll
                        for (int j = 0; j < 3; ++j) cnts[quad * 4 + r][w][j] = c[j];
                }
            }
            __syncthreads();
            if (t < 16) {
                int d[3] = {0, 0, 0};
#pragma unroll
                for (int ww = 0; ww < 8; ++ww)
#pragma unroll
                    for (int j = 0; j < 3; ++j) d[j] += cnts[t][ww][j];
                float lo = rowLo[t], hi = rowHi[t];
                const float w4 = __fmul_rn(__fsub_rn(hi, lo), 0.25f);
                const float t1 = __fmaf_rn(w4, 1.f, lo);
                const float t2 = __fmaf_rn(w4, 2.f, lo);
                const float t3 = __fmaf_rn(w4, 3.f, lo);
                if (d[2] >= TOPK)      { lo = t3; }
                else if (d[1] >= TOPK) { lo = t2; hi = t3; }
                else if (d[0] >= TOPK) { lo = t1; hi = t2; }
                else                   { hi = t1; }
                rowLo[t] = lo;
                rowHi[t] = hi;
            }
            __syncthreads();
        }

        // ---- sparse softmax (|s| small: raw exp is safe) -------------------
        float kth[4], zp[4] = {0.f, 0.f, 0.f, 0.f};
#pragma unroll
        for (int r = 0; r < 4; ++r) kth[r] = rowLo[quad * 4 + r];
#pragma unroll
        for (int tt = 0; tt < 16; ++tt)
#pragma unroll
            for (int r = 0; r < 4; ++r) {
                const float v = acc[tt][r];
                const float e = (v >= kth[r]) ? __expf(v) : 0.f;
                acc[tt][r] = e;
                zp[r] += e;
            }
#pragma unroll
        for (int off = 1; off < 16; off <<= 1)
#pragma unroll
            for (int r = 0; r < 4; ++r) zp[r] += __shfl_xor(zp[r], off, 16);
        if (lq == 0)
#pragma unroll
            for (int r = 0; r < 4; ++r) red[quad * 4 + r][w][0] = zp[r];
        __syncthreads();
        if (t < 16) {
            float z = 0.f;
#pragma unroll
            for (int ww = 0; ww < 8; ++ww) z += red[t][ww][0];
            rowZi[t] = 1.f / z;
        }
        __syncthreads();
        float zi[4];
#pragma unroll
        for (int r = 0; r < 4; ++r) zi[r] = rowZi[quad * 4 + r];

        // ---- normalize, stage attn bf16 for PV, accumulate avg in global ---
        // (atomic RMW is fire-and-forget; region is L3-resident. 16
        //  commutative contributors per cell across the whole grid.)
        {
            float* avrow = avg + ((size_t)(b * S_LEN + q0 + quad * 4)) * S_LEN
                         + w * 256 + lq;
#pragma unroll
            for (int tt = 0; tt < 16; ++tt)
#pragma unroll
                for (int r = 0; r < 4; ++r) {
                    const float a_ = acc[tt][r] * zi[r];
                    aLds[(quad * 4 + r) * 2056 + w * 256 + tt * 16 + lq] = f2b(a_);
                    atomicAdd(avrow + (size_t)r * S_LEN + tt * 16, a_ * (1.f / NHEAD));
                }
        }
        __syncthreads();

        // ---- PV: wave w -> e-tile (w&3), j-half (w>>2); 32 K-steps ---------
        const int et = w & 3, jh = w >> 2;
        const u16* vb = Vt + ((size_t)(b * NHEAD + h) * HD + et * 16 + lq) * S_LEN
                        + jh * 1024 + quad * 8;
        const u16* ab = aLds + lq * 2056 + jh * 1024 + quad * 8;
        f32x4 pv = {0.f, 0.f, 0.f, 0.f};
#pragma unroll 8
        for (int st = 0; st < 32; ++st) {
            const bf16x8 af = *(const bf16x8*)(ab + st * 32);
            const bf16x8 vf = *(const bf16x8*)(vb + st * 32);
            pv = MFMA(af, vf, pv, 0, 0, 0);
        }
        if (w >= 4) {
#pragma unroll
            for (int r = 0; r < 4; ++r)
                pvpart[(et * 16 + quad * 4 + r) * 16 + lq] = pv[r];
        }
        __syncthreads();
        if (w < 4) {
#pragma unroll
            for (int r = 0; r < 4; ++r) {
                const float v = pv[r] + pvpart[(et * 16 + quad * 4 + r) * 16 + lq];
                const size_t idx =
                    ((size_t)(b * S_LEN + q0 + quad * 4 + r)) * D_DIM + h * HD + et * 16 + lq;
                const u16 hv = f2b(v);
                HOhi[idx] = hv;
                HOlo[idx] = f2b(v - b2f(hv));
            }
        }
    } // heads
}

// ---------------------------------------------------------------------------
extern "C" void kernel_launch(void* const* d_in, const int* in_sizes, int n_in,
                              void* d_out, int out_size, void* d_ws, size_t ws_size,
                              hipStream_t stream)
{
    const float* x    = (const float*)d_in[0];
    const float* Wq   = (const float*)d_in[1];
    const float* bq   = (const float*)d_in[2];
    const float* Wk   = (const float*)d_in[3];
    const float* bk   = (const float*)d_in[4];
    const float* Wv   = (const float*)d_in[5];
    const float* bv   = (const float*)d_in[6];
    const float* Wo   = (const float*)d_in[7];
    const float* bo   = (const float*)d_in[8];
    const float* temp = (const float*)d_in[9];
    float* out = (float*)d_out;

    const int B = in_sizes[0] / (S_LEN * D_DIM);   // 2
    const int M = B * S_LEN;                       // 4096
    const size_t NQ = (size_t)M * D_DIM;
    const size_t NW = (size_t)D_DIM * D_DIM;

    u16* Qhi = (u16*)d_ws;
    u16* Qlo = Qhi + NQ;
    u16* Khi = Qlo + NQ;
    u16* Klo = Khi + NQ;
    u16* Vt  = Klo + NQ;
    u16* Xhi = Vt  + NQ;   // reused as HOhi after QKV GEMMs
    u16* Xlo = Xhi + NQ;   // reused as HOlo
    u16* Wqh = Xlo + NQ;
    u16* Wql = Wqh + NW;
    u16* Wkh = Wql + NW;
    u16* Wkl = Wkh + NW;
    u16* Wvh = Wkl + NW;
    u16* Wvl = Wvh + NW;
    u16* Woh = Wvl + NW;
    u16* Wol = Woh + NW;
    float* avg = out + NQ;

    const int n4x = (int)(NQ / 4), n4w = (int)(NW / 4);
    const int n4a = (int)((size_t)M * S_LEN / 4);
    zero_f32<<<(n4a + 255) / 256, 256, 0, stream>>>(avg, n4a);
    split_f32<<<(n4x + 255) / 256, 256, 0, stream>>>(x,  Xhi, Xlo, n4x);
    split_f32<<<(n4w + 255) / 256, 256, 0, stream>>>(Wq, Wqh, Wql, n4w);
    split_f32<<<(n4w + 255) / 256, 256, 0, stream>>>(Wk, Wkh, Wkl, n4w);
    split_f32<<<(n4w + 255) / 256, 256, 0, stream>>>(Wv, Wvh, Wvl, n4w);
    split_f32<<<(n4w + 255) / 256, 256, 0, stream>>>(Wo, Woh, Wol, n4w);

    dim3 gg(D_DIM / 128, M / 128, 1);
    proj_mfma<0><<<gg, 512, 0, stream>>>(Xhi, Xlo, Wqh, Wql, bq, nullptr, Qhi, Qlo);
    proj_mfma<0><<<gg, 512, 0, stream>>>(Xhi, Xlo, Wkh, Wkl, bk, nullptr, Khi, Klo);
    proj_mfma<1><<<gg, 512, 0, stream>>>(Xhi, Xlo, Wvh, Wvl, bv, nullptr, Vt, nullptr);

    attn_mfma<<<dim3(M / 16, 2), 512, 0, stream>>>(Qhi, Qlo, Khi, Klo, Vt, temp,
                                                   Xhi, Xlo, avg);

    proj_mfma<2><<<gg, 512, 0, stream>>>(Xhi, Xlo, Woh, Wol, bo, out, nullptr, nullptr);
}

// Round 7
// 1179.608 us; speedup vs baseline: 2.9326x; 2.9326x over previous
//
#include <hip/hip_runtime.h>
#include <stdint.h>

#define S_LEN 2048
#define D_DIM 1024
#define NHEAD 16
#define HD    64
#define TOPK  409   // max(1, int(2048*(1.0-0.8)))

typedef unsigned short u16;
typedef __attribute__((ext_vector_type(8))) short bf16x8;
typedef __attribute__((ext_vector_type(4))) float f32x4;
#define MFMA __builtin_amdgcn_mfma_f32_16x16x32_bf16

__device__ __forceinline__ u16 f2b(float f) {                // fp32 -> bf16 RNE
    unsigned u = __float_as_uint(f);
    return (u16)((u + 0x7fffu + ((u >> 16) & 1u)) >> 16);
}
__device__ __forceinline__ float b2f(u16 h) {
    return __uint_as_float(((unsigned)h) << 16);
}

// ---------------------------------------------------------------------------
// fp32 -> bf16 hi/lo split (hi+lo reproduces fp32 to ~2^-16 rel)
// ---------------------------------------------------------------------------
__global__ __launch_bounds__(256, 4)
void split_f32(const float* __restrict__ src, u16* __restrict__ hi,
               u16* __restrict__ lo, int n4)
{
    const int i = blockIdx.x * 256 + threadIdx.x;
    if (i >= n4) return;
    const float4 v = ((const float4*)src)[i];
    const float vv[4] = {v.x, v.y, v.z, v.w};
    u16 h4[4], l4[4];
#pragma unroll
    for (int c = 0; c < 4; ++c) {
        h4[c] = f2b(vv[c]);
        l4[c] = f2b(vv[c] - b2f(h4[c]));
    }
    ((ushort4*)hi)[i] = make_ushort4(h4[0], h4[1], h4[2], h4[3]);
    ((ushort4*)lo)[i] = make_ushort4(l4[0], l4[1], l4[2], l4[3]);
}

// ---------------------------------------------------------------------------
// Fused 4-way weight split: blockIdx.y selects among {Wq,Wk,Wv,Wo}.
// Saves 3 kernel-launch overheads vs 4 separate split_f32 launches.
// ---------------------------------------------------------------------------
__global__ __launch_bounds__(256, 4)
void split4_f32(const float* __restrict__ s0, const float* __restrict__ s1,
                const float* __restrict__ s2, const float* __restrict__ s3,
                u16* __restrict__ h0, u16* __restrict__ l0,
                u16* __restrict__ h1, u16* __restrict__ l1,
                u16* __restrict__ h2, u16* __restrict__ l2,
                u16* __restrict__ h3, u16* __restrict__ l3, int n4)
{
    const int i = blockIdx.x * 256 + threadIdx.x;
    if (i >= n4) return;
    const int y = blockIdx.y;
    const float* src = (y == 0) ? s0 : (y == 1) ? s1 : (y == 2) ? s2 : s3;
    u16* hi = (y == 0) ? h0 : (y == 1) ? h1 : (y == 2) ? h2 : h3;
    u16* lo = (y == 0) ? l0 : (y == 1) ? l1 : (y == 2) ? l2 : l3;
    const float4 v = ((const float4*)src)[i];
    const float vv[4] = {v.x, v.y, v.z, v.w};
    u16 h4[4], l4[4];
#pragma unroll
    for (int c = 0; c < 4; ++c) {
        h4[c] = f2b(vv[c]);
        l4[c] = f2b(vv[c] - b2f(h4[c]));
    }
    ((ushort4*)hi)[i] = make_ushort4(h4[0], h4[1], h4[2], h4[3]);
    ((ushort4*)lo)[i] = make_ushort4(l4[0], l4[1], l4[2], l4[3]);
}

// ---------------------------------------------------------------------------
// Projection GEMM via 3x bf16-split MFMA: Out = A @ W^T + bias.
// A: [M x 1024] (hi/lo bf16), W: [1024 x 1024] row-major k-contig (hi/lo).
// Block 512 thr = 8 waves; block tile 128x128; wave tile 64(m) x 32(n).
// MODE 0: Q/K -> o1/o2 hi/lo bf16 in [b,h,s,e]. MODE 1: V -> o1 bf16 in
// [b,h,e,s] (pre-transposed for PV). MODE 2: fp32 out[m][n].
// ---------------------------------------------------------------------------
template<int MODE>
__global__ __launch_bounds__(512, 2)
void proj_mfma(const u16* __restrict__ Ahi, const u16* __restrict__ Alo,
               const u16* __restrict__ Whi, const u16* __restrict__ Wlo,
               const float* __restrict__ bias, float* __restrict__ outf,
               u16* __restrict__ o1, u16* __restrict__ o2)
{
    const int t = threadIdx.x, w = t >> 6, l = t & 63;
    const int lq = l & 15, quad = l >> 4;
    const int m0 = blockIdx.y * 128 + (w >> 2) * 64;
    const int n0 = blockIdx.x * 128 + (w & 3) * 32;

    f32x4 acc[4][2];
#pragma unroll
    for (int i = 0; i < 4; ++i)
#pragma unroll
        for (int j = 0; j < 2; ++j) acc[i][j] = (f32x4){0.f, 0.f, 0.f, 0.f};

    const size_t abase = (size_t)(m0 + lq) * D_DIM + quad * 8;
    const size_t bbase = (size_t)(n0 + lq) * D_DIM + quad * 8;

#pragma unroll 2
    for (int k0 = 0; k0 < D_DIM; k0 += 32) {
        bf16x8 ah[4], al[4], bh[2], bl[2];
#pragma unroll
        for (int i = 0; i < 4; ++i) {
            ah[i] = *(const bf16x8*)(Ahi + abase + (size_t)i * 16 * D_DIM + k0);
            al[i] = *(const bf16x8*)(Alo + abase + (size_t)i * 16 * D_DIM + k0);
        }
#pragma unroll
        for (int j = 0; j < 2; ++j) {
            bh[j] = *(const bf16x8*)(Whi + bbase + (size_t)j * 16 * D_DIM + k0);
            bl[j] = *(const bf16x8*)(Wlo + bbase + (size_t)j * 16 * D_DIM + k0);
        }
#pragma unroll
        for (int i = 0; i < 4; ++i)
#pragma unroll
            for (int j = 0; j < 2; ++j) {
                acc[i][j] = MFMA(ah[i], bh[j], acc[i][j], 0, 0, 0);
                acc[i][j] = MFMA(ah[i], bl[j], acc[i][j], 0, 0, 0);
                acc[i][j] = MFMA(al[i], bh[j], acc[i][j], 0, 0, 0);
            }
    }

#pragma unroll
    for (int j = 0; j < 2; ++j) {
        const int n = n0 + j * 16 + lq;
        const float bb = bias[n];
        const int hh = n >> 6, ee = n & 63;
#pragma unroll
        for (int i = 0; i < 4; ++i) {
            const int mb = m0 + i * 16 + quad * 4;
            const int bbm = mb >> 11, ss = mb & 2047;
            if (MODE == 2) {
#pragma unroll
                for (int r = 0; r < 4; ++r)
                    outf[(size_t)(mb + r) * D_DIM + n] = acc[i][j][r] + bb;
            } else if (MODE == 1) {
                ushort4 pk;
                pk.x = f2b(acc[i][j][0] + bb);
                pk.y = f2b(acc[i][j][1] + bb);
                pk.z = f2b(acc[i][j][2] + bb);
                pk.w = f2b(acc[i][j][3] + bb);
                *(ushort4*)(o1 + ((size_t)((bbm * NHEAD + hh) * HD + ee)) * S_LEN + ss) = pk;
            } else {
#pragma unroll
                for (int r = 0; r < 4; ++r) {
                    const float v = acc[i][j][r] + bb;
                    const size_t idx = ((size_t)(bbm * NHEAD + hh) * S_LEN + ss + r) * HD + ee;
                    const u16 h = f2b(v);
                    o1[idx] = h;
                    o2[idx] = f2b(v - b2f(h));
                }
            }
        }
    }
}

// ---------------------------------------------------------------------------
// Attention: block = 512 thr (8 waves) owns (b, 16 q-rows), loops 16 heads.
// (Verified R0 structure: 748 us. Occupancy-raising variants all failed:
//  wider blocks widen barriers (R1), head-split duplicates work at same
//  occupancy (R2), and any __launch_bounds__(512,4) register diet makes the
//  allocator spill acc[16] to scratch -> GBs of FETCH (R4-R6). 1 block/CU
//  with 128 VGPR + AGPR acc is this compiler's fixed point.)
// Scores: 3xBF16-split MFMA, fp32 acc in regs (wave w owns cols w*256..+255;
// lane: rows quad*4+r, col tt*16+lq). Top-k threshold: mu/sigma-seeded
// bisection COUNT select (no LDS atomics): round 0 on z-grid, 5 quadrisection
// rounds -> threshold within ~6e-5 of exact kth (count 409 +/- 1).
// Softmax fp32, PV bf16 MFMA via LDS-staged attn, HO written bf16 hi/lo.
// ---------------------------------------------------------------------------
__global__ __launch_bounds__(512, 2)
void attn_mfma(const u16* __restrict__ Qhi, const u16* __restrict__ Qlo,
               const u16* __restrict__ Khi, const u16* __restrict__ Klo,
               const u16* __restrict__ Vt,  const float* __restrict__ temp,
               u16* __restrict__ HOhi, u16* __restrict__ HOlo,
               float* __restrict__ avg)
{
    __shared__ __align__(16) u16 aLds[16 * 2056];  // attn bf16, stride 2056
    __shared__ float pvpart[4 * 16 * 16];          // PV j-half partials
    __shared__ int   cnts[16][8][5];               // per-row per-wave counts
    __shared__ float red[16][8][2];                // mu/var (and Z) partials
    __shared__ float rowMu[16], rowSig[16], rowLo[16], rowHi[16], rowZi[16];

    const int t = threadIdx.x, w = t >> 6, l = t & 63;
    const int lq = l & 15, quad = l >> 4;
    const int b  = blockIdx.x >> 7;
    const int q0 = (blockIdx.x & 127) << 4;

    float avgreg[64];
#pragma unroll
    for (int i = 0; i < 64; ++i) avgreg[i] = 0.f;

#pragma unroll 1
    for (int h = 0; h < NHEAD; ++h) {
        const size_t bh = (size_t)(b * NHEAD + h) * S_LEN;
        const float tscale = 0.125f / fmaxf(temp[h], 0.1f);

        // ---- Q fragments (A-operand: lane -> row lq, k = quad*8..) --------
        const u16* qph = Qhi + (bh + q0 + lq) * HD + quad * 8;
        const u16* qpl = Qlo + (bh + q0 + lq) * HD + quad * 8;
        const bf16x8 qh0 = *(const bf16x8*)qph;
        const bf16x8 qh1 = *(const bf16x8*)(qph + 32);
        const bf16x8 ql0 = *(const bf16x8*)qpl;
        const bf16x8 ql1 = *(const bf16x8*)(qpl + 32);

        // ---- scores over this wave's 256-col chunk -------------------------
        f32x4 acc[16];
        const u16* kph = Khi + (bh + w * 256 + lq) * HD + quad * 8;
        const u16* kpl = Klo + (bh + w * 256 + lq) * HD + quad * 8;
#pragma unroll
        for (int tt = 0; tt < 16; ++tt) {
            const bf16x8 k0 = *(const bf16x8*)(kph + tt * 16 * HD);
            const bf16x8 k1 = *(const bf16x8*)(kph + tt * 16 * HD + 32);
            const bf16x8 m0 = *(const bf16x8*)(kpl + tt * 16 * HD);
            const bf16x8 m1 = *(const bf16x8*)(kpl + tt * 16 * HD + 32);
            f32x4 a = {0.f, 0.f, 0.f, 0.f};
            a = MFMA(qh0, k0, a, 0, 0, 0);
            a = MFMA(qh1, k1, a, 0, 0, 0);
            a = MFMA(qh0, m0, a, 0, 0, 0);
            a = MFMA(qh1, m1, a, 0, 0, 0);
            a = MFMA(ql0, k0, a, 0, 0, 0);
            a = MFMA(ql1, k1, a, 0, 0, 0);
            acc[tt] = a * tscale;
        }
        __syncthreads();   // B0: prev head fully done with LDS

        // ---- per-row mean / sigma ------------------------------------------
        {
            float s1[4] = {0.f,0.f,0.f,0.f}, s2[4] = {0.f,0.f,0.f,0.f};
#pragma unroll
            for (int tt = 0; tt < 16; ++tt)
#pragma unroll
                for (int r = 0; r < 4; ++r) {
                    const float v = acc[tt][r];
                    s1[r] += v;
                    s2[r] = __fmaf_rn(v, v, s2[r]);
                }
#pragma unroll
            for (int off = 1; off < 16; off <<= 1)
#pragma unroll
                for (int r = 0; r < 4; ++r) {
                    s1[r] += __shfl_xor(s1[r], off, 16);
                    s2[r] += __shfl_xor(s2[r], off, 16);
                }
            if (lq == 0)
#pragma unroll
                for (int r = 0; r < 4; ++r) {
                    red[quad * 4 + r][w][0] = s1[r];
                    red[quad * 4 + r][w][1] = s2[r];
                }
        }
        __syncthreads();   // B1
        if (t < 16) {
            float a = 0.f, c = 0.f;
#pragma unroll
            for (int ww = 0; ww < 8; ++ww) { a += red[t][ww][0]; c += red[t][ww][1]; }
            const float mu = a * (1.f / 2048.f);
            const float va = c * (1.f / 2048.f) - mu * mu;
            rowMu[t] = mu;
            rowSig[t] = sqrtf(fmaxf(va, 0.f));
        }
        __syncthreads();   // B2

        // ---- round 0: z-grid {0.55..1.15} + out-of-bracket fallback --------
        {
            float th[5][4];
            int c[5][4];
#pragma unroll
            for (int r = 0; r < 4; ++r) {
                const float mu = rowMu[quad * 4 + r], sg = rowSig[quad * 4 + r];
#pragma unroll
                for (int i = 0; i < 5; ++i) {
                    th[i][r] = __fmaf_rn(sg, 0.55f + 0.15f * (float)i, mu);
                    c[i][r] = 0;
                }
            }
#pragma unroll
            for (int tt = 0; tt < 16; ++tt)
#pragma unroll
                for (int r = 0; r < 4; ++r) {
                    const float v = acc[tt][r];
#pragma unroll
                    for (int i = 0; i < 5; ++i) c[i][r] += (v >= th[i][r]) ? 1 : 0;
                }
#pragma unroll
            for (int off = 1; off < 16; off <<= 1)
#pragma unroll
                for (int i = 0; i < 5; ++i)
#pragma unroll
                    for (int r = 0; r < 4; ++r) c[i][r] += __shfl_xor(c[i][r], off, 16);
            if (lq == 0)
#pragma unroll
                for (int r = 0; r < 4; ++r)
#pragma unroll
                    for (int i = 0; i < 5; ++i) cnts[quad * 4 + r][w][i] = c[i][r];
        }
        __syncthreads();   // B3
        if (t < 16) {
            int c[5] = {0, 0, 0, 0, 0};
#pragma unroll
            for (int ww = 0; ww < 8; ++ww)
#pragma unroll
                for (int i = 0; i < 5; ++i) c[i] += cnts[t][ww][i];
            const float mu = rowMu[t], sg = rowSig[t];
            float lo, hi;
            if (c[0] < TOPK) {
                lo = __fmaf_rn(sg, -6.f, mu);
                hi = __fmaf_rn(sg, 0.55f + 0.15f * 0.f, mu);
            } else if (c[4] >= TOPK) {
                lo = __fmaf_rn(sg, 0.55f + 0.15f * 4.f, mu);
                hi = __fmaf_rn(sg, 6.f, mu);
            } else {
                int bi = 0;
#pragma unroll
                for (int j = 1; j < 4; ++j) if (c[j] >= TOPK) bi = j;
                lo = __fmaf_rn(sg, 0.55f + 0.15f * (float)bi, mu);
                hi = __fmaf_rn(sg, 0.55f + 0.15f * (float)(bi + 1), mu);
            }
            rowLo[t] = lo;
            rowHi[t] = hi;
        }
        __syncthreads();   // B4

        // ---- 5 quadrisection refine rounds ---------------------------------
#pragma unroll 1
        for (int rd = 0; rd < 5; ++rd) {
            {
                float th[3][4];
                int c[3][4];
#pragma unroll
                for (int r = 0; r < 4; ++r) {
                    const float lo_ = rowLo[quad * 4 + r], hi_ = rowHi[quad * 4 + r];
                    const float w4 = __fmul_rn(__fsub_rn(hi_, lo_), 0.25f);
#pragma unroll
                    for (int j = 0; j < 3; ++j) {
                        th[j][r] = __fmaf_rn(w4, (float)(j + 1), lo_);
                        c[j][r] = 0;
                    }
                }
#pragma unroll
                for (int tt = 0; tt < 16; ++tt)
#pragma unroll
                    for (int r = 0; r < 4; ++r) {
                        const float v = acc[tt][r];
#pragma unroll
                        for (int j = 0; j < 3; ++j) c[j][r] += (v >= th[j][r]) ? 1 : 0;
                    }
#pragma unroll
                for (int off = 1; off < 16; off <<= 1)
#pragma unroll
                    for (int j = 0; j < 3; ++j)
#pragma unroll
                        for (int r = 0; r < 4; ++r) c[j][r] += __shfl_xor(c[j][r], off, 16);
                if (lq == 0)
#pragma unroll
                    for (int r = 0; r < 4; ++r)
#pragma unroll
                        for (int j = 0; j < 3; ++j) cnts[quad * 4 + r][w][j] = c[j][r];
            }
            __syncthreads();
            if (t < 16) {
                int d[3] = {0, 0, 0};
#pragma unroll
                for (int ww = 0; ww < 8; ++ww)
#pragma unroll
                    for (int j = 0; j < 3; ++j) d[j] += cnts[t][ww][j];
                float lo = rowLo[t], hi = rowHi[t];
                const float w4 = __fmul_rn(__fsub_rn(hi, lo), 0.25f);
                const float t1 = __fmaf_rn(w4, 1.f, lo);
                const float t2 = __fmaf_rn(w4, 2.f, lo);
                const float t3 = __fmaf_rn(w4, 3.f, lo);
                if (d[2] >= TOPK)      { lo = t3; }
                else if (d[1] >= TOPK) { lo = t2; hi = t3; }
                else if (d[0] >= TOPK) { lo = t1; hi = t2; }
                else                   { hi = t1; }
                rowLo[t] = lo;
                rowHi[t] = hi;
            }
            __syncthreads();
        }

        // ---- sparse softmax (|s| small: raw exp is safe) -------------------
        float kth[4], zp[4] = {0.f, 0.f, 0.f, 0.f};
#pragma unroll
        for (int r = 0; r < 4; ++r) kth[r] = rowLo[quad * 4 + r];
#pragma unroll
        for (int tt = 0; tt < 16; ++tt)
#pragma unroll
            for (int r = 0; r < 4; ++r) {
                const float v = acc[tt][r];
                const float e = (v >= kth[r]) ? __expf(v) : 0.f;
                acc[tt][r] = e;
                zp[r] += e;
            }
#pragma unroll
        for (int off = 1; off < 16; off <<= 1)
#pragma unroll
            for (int r = 0; r < 4; ++r) zp[r] += __shfl_xor(zp[r], off, 16);
        if (lq == 0)
#pragma unroll
            for (int r = 0; r < 4; ++r) red[quad * 4 + r][w][0] = zp[r];
        __syncthreads();
        if (t < 16) {
            float z = 0.f;
#pragma unroll
            for (int ww = 0; ww < 8; ++ww) z += red[t][ww][0];
            rowZi[t] = 1.f / z;
        }
        __syncthreads();
        float zi[4];
#pragma unroll
        for (int r = 0; r < 4; ++r) zi[r] = rowZi[quad * 4 + r];

        // ---- normalize, accumulate avg, stage attn bf16 for PV -------------
#pragma unroll
        for (int tt = 0; tt < 16; ++tt)
#pragma unroll
            for (int r = 0; r < 4; ++r) {
                const float a_ = acc[tt][r] * zi[r];
                avgreg[tt * 4 + r] += a_;
                aLds[(quad * 4 + r) * 2056 + w * 256 + tt * 16 + lq] = f2b(a_);
            }
        __syncthreads();

        // ---- PV: wave w -> e-tile (w&3), j-half (w>>2); 32 K-steps ---------
        const int et = w & 3, jh = w >> 2;
        const u16* vb = Vt + ((size_t)(b * NHEAD + h) * HD + et * 16 + lq) * S_LEN
                        + jh * 1024 + quad * 8;
        const u16* ab = aLds + lq * 2056 + jh * 1024 + quad * 8;
        f32x4 pv = {0.f, 0.f, 0.f, 0.f};
#pragma unroll 8
        for (int st = 0; st < 32; ++st) {
            const bf16x8 af = *(const bf16x8*)(ab + st * 32);
            const bf16x8 vf = *(const bf16x8*)(vb + st * 32);
            pv = MFMA(af, vf, pv, 0, 0, 0);
        }
        if (w >= 4) {
#pragma unroll
            for (int r = 0; r < 4; ++r)
                pvpart[(et * 16 + quad * 4 + r) * 16 + lq] = pv[r];
        }
        __syncthreads();
        if (w < 4) {
#pragma unroll
            for (int r = 0; r < 4; ++r) {
                const float v = pv[r] + pvpart[(et * 16 + quad * 4 + r) * 16 + lq];
                const size_t idx =
                    ((size_t)(b * S_LEN + q0 + quad * 4 + r)) * D_DIM + h * HD + et * 16 + lq;
                const u16 hv = f2b(v);
                HOhi[idx] = hv;
                HOlo[idx] = f2b(v - b2f(hv));
            }
        }
    } // heads

    // ---- avg_attention = mean over heads -----------------------------------
#pragma unroll
    for (int tt = 0; tt < 16; ++tt)
#pragma unroll
        for (int r = 0; r < 4; ++r)
            avg[((size_t)(b * S_LEN + q0 + quad * 4 + r)) * S_LEN + w * 256 + tt * 16 + lq] =
                avgreg[tt * 4 + r] * (1.f / NHEAD);
}

// ---------------------------------------------------------------------------
extern "C" void kernel_launch(void* const* d_in, const int* in_sizes, int n_in,
                              void* d_out, int out_size, void* d_ws, size_t ws_size,
                              hipStream_t stream)
{
    const float* x    = (const float*)d_in[0];
    const float* Wq   = (const float*)d_in[1];
    const float* bq   = (const float*)d_in[2];
    const float* Wk   = (const float*)d_in[3];
    const float* bk   = (const float*)d_in[4];
    const float* Wv   = (const float*)d_in[5];
    const float* bv   = (const float*)d_in[6];
    const float* Wo   = (const float*)d_in[7];
    const float* bo   = (const float*)d_in[8];
    const float* temp = (const float*)d_in[9];
    float* out = (float*)d_out;

    const int B = in_sizes[0] / (S_LEN * D_DIM);   // 2
    const int M = B * S_LEN;                       // 4096
    const size_t NQ = (size_t)M * D_DIM;
    const size_t NW = (size_t)D_DIM * D_DIM;

    u16* Qhi = (u16*)d_ws;
    u16* Qlo = Qhi + NQ;
    u16* Khi = Qlo + NQ;
    u16* Klo = Khi + NQ;
    u16* Vt  = Klo + NQ;
    u16* Xhi = Vt  + NQ;   // reused as HOhi after QKV GEMMs
    u16* Xlo = Xhi + NQ;   // reused as HOlo
    u16* Wqh = Xlo + NQ;
    u16* Wql = Wqh + NW;
    u16* Wkh = Wql + NW;
    u16* Wkl = Wkh + NW;
    u16* Wvh = Wkl + NW;
    u16* Wvl = Wvh + NW;
    u16* Woh = Wvl + NW;
    u16* Wol = Woh + NW;
    float* avg = out + NQ;

    const int n4x = (int)(NQ / 4), n4w = (int)(NW / 4);
    split_f32<<<(n4x + 255) / 256, 256, 0, stream>>>(x, Xhi, Xlo, n4x);
    split4_f32<<<dim3((n4w + 255) / 256, 4), 256, 0, stream>>>(
        Wq, Wk, Wv, Wo, Wqh, Wql, Wkh, Wkl, Wvh, Wvl, Woh, Wol, n4w);

    dim3 gg(D_DIM / 128, M / 128, 1);
    proj_mfma<0><<<gg, 512, 0, stream>>>(Xhi, Xlo, Wqh, Wql, bq, nullptr, Qhi, Qlo);
    proj_mfma<0><<<gg, 512, 0, stream>>>(Xhi, Xlo, Wkh, Wkl, bk, nullptr, Khi, Klo);
    proj_mfma<1><<<gg, 512, 0, stream>>>(Xhi, Xlo, Wvh, Wvl, bv, nullptr, Vt, nullptr);

    attn_mfma<<<dim3(M / 16), 512, 0, stream>>>(Qhi, Qlo, Khi, Klo, Vt, temp,
                                                Xhi, Xlo, avg);

    proj_mfma<2><<<gg, 512, 0, stream>>>(Xhi, Xlo, Woh, Wol, bo, out, nullptr, nullptr);
}

// Round 8
// 1059.875 us; speedup vs baseline: 3.2638x; 1.1130x over previous
//
#include <hip/hip_runtime.h>
#include <stdint.h>

#define S_LEN 2048
#define D_DIM 1024
#define NHEAD 16
#define HD    64
#define TOPK  409   // max(1, int(2048*(1.0-0.8)))

typedef unsigned short u16;
typedef __attribute__((ext_vector_type(8))) short bf16x8;
typedef __attribute__((ext_vector_type(4))) float f32x4;
#define MFMA __builtin_amdgcn_mfma_f32_16x16x32_bf16

__device__ __forceinline__ u16 f2b(float f) {                // fp32 -> bf16 RNE
    unsigned u = __float_as_uint(f);
    return (u16)((u + 0x7fffu + ((u >> 16) & 1u)) >> 16);
}
__device__ __forceinline__ float b2f(u16 h) {
    return __uint_as_float(((unsigned)h) << 16);
}

// ---------------------------------------------------------------------------
// fp32 -> bf16 hi/lo split (hi+lo reproduces fp32 to ~2^-16 rel)
// ---------------------------------------------------------------------------
__global__ __launch_bounds__(256, 4)
void split_f32(const float* __restrict__ src, u16* __restrict__ hi,
               u16* __restrict__ lo, int n4)
{
    const int i = blockIdx.x * 256 + threadIdx.x;
    if (i >= n4) return;
    const float4 v = ((const float4*)src)[i];
    const float vv[4] = {v.x, v.y, v.z, v.w};
    u16 h4[4], l4[4];
#pragma unroll
    for (int c = 0; c < 4; ++c) {
        h4[c] = f2b(vv[c]);
        l4[c] = f2b(vv[c] - b2f(h4[c]));
    }
    ((ushort4*)hi)[i] = make_ushort4(h4[0], h4[1], h4[2], h4[3]);
    ((ushort4*)lo)[i] = make_ushort4(l4[0], l4[1], l4[2], l4[3]);
}

// ---------------------------------------------------------------------------
// Fused 4-way weight split: blockIdx.y selects among {Wq,Wk,Wv,Wo}.
// ---------------------------------------------------------------------------
__global__ __launch_bounds__(256, 4)
void split4_f32(const float* __restrict__ s0, const float* __restrict__ s1,
                const float* __restrict__ s2, const float* __restrict__ s3,
                u16* __restrict__ h0, u16* __restrict__ l0,
                u16* __restrict__ h1, u16* __restrict__ l1,
                u16* __restrict__ h2, u16* __restrict__ l2,
                u16* __restrict__ h3, u16* __restrict__ l3, int n4)
{
    const int i = blockIdx.x * 256 + threadIdx.x;
    if (i >= n4) return;
    const int y = blockIdx.y;
    const float* src = (y == 0) ? s0 : (y == 1) ? s1 : (y == 2) ? s2 : s3;
    u16* hi = (y == 0) ? h0 : (y == 1) ? h1 : (y == 2) ? h2 : h3;
    u16* lo = (y == 0) ? l0 : (y == 1) ? l1 : (y == 2) ? l2 : l3;
    const float4 v = ((const float4*)src)[i];
    const float vv[4] = {v.x, v.y, v.z, v.w};
    u16 h4[4], l4[4];
#pragma unroll
    for (int c = 0; c < 4; ++c) {
        h4[c] = f2b(vv[c]);
        l4[c] = f2b(vv[c] - b2f(h4[c]));
    }
    ((ushort4*)hi)[i] = make_ushort4(h4[0], h4[1], h4[2], h4[3]);
    ((ushort4*)lo)[i] = make_ushort4(l4[0], l4[1], l4[2], l4[3]);
}

// ---------------------------------------------------------------------------
// Projection GEMM via 3x bf16-split MFMA: Out = A @ W^T + bias.
// ---------------------------------------------------------------------------
template<int MODE>
__global__ __launch_bounds__(512, 2)
void proj_mfma(const u16* __restrict__ Ahi, const u16* __restrict__ Alo,
               const u16* __restrict__ Whi, const u16* __restrict__ Wlo,
               const float* __restrict__ bias, float* __restrict__ outf,
               u16* __restrict__ o1, u16* __restrict__ o2)
{
    const int t = threadIdx.x, w = t >> 6, l = t & 63;
    const int lq = l & 15, quad = l >> 4;
    const int m0 = blockIdx.y * 128 + (w >> 2) * 64;
    const int n0 = blockIdx.x * 128 + (w & 3) * 32;

    f32x4 acc[4][2];
#pragma unroll
    for (int i = 0; i < 4; ++i)
#pragma unroll
        for (int j = 0; j < 2; ++j) acc[i][j] = (f32x4){0.f, 0.f, 0.f, 0.f};

    const size_t abase = (size_t)(m0 + lq) * D_DIM + quad * 8;
    const size_t bbase = (size_t)(n0 + lq) * D_DIM + quad * 8;

#pragma unroll 2
    for (int k0 = 0; k0 < D_DIM; k0 += 32) {
        bf16x8 ah[4], al[4], bh[2], bl[2];
#pragma unroll
        for (int i = 0; i < 4; ++i) {
            ah[i] = *(const bf16x8*)(Ahi + abase + (size_t)i * 16 * D_DIM + k0);
            al[i] = *(const bf16x8*)(Alo + abase + (size_t)i * 16 * D_DIM + k0);
        }
#pragma unroll
        for (int j = 0; j < 2; ++j) {
            bh[j] = *(const bf16x8*)(Whi + bbase + (size_t)j * 16 * D_DIM + k0);
            bl[j] = *(const bf16x8*)(Wlo + bbase + (size_t)j * 16 * D_DIM + k0);
        }
#pragma unroll
        for (int i = 0; i < 4; ++i)
#pragma unroll
            for (int j = 0; j < 2; ++j) {
                acc[i][j] = MFMA(ah[i], bh[j], acc[i][j], 0, 0, 0);
                acc[i][j] = MFMA(ah[i], bl[j], acc[i][j], 0, 0, 0);
                acc[i][j] = MFMA(al[i], bh[j], acc[i][j], 0, 0, 0);
            }
    }

#pragma unroll
    for (int j = 0; j < 2; ++j) {
        const int n = n0 + j * 16 + lq;
        const float bb = bias[n];
        const int hh = n >> 6, ee = n & 63;
#pragma unroll
        for (int i = 0; i < 4; ++i) {
            const int mb = m0 + i * 16 + quad * 4;
            const int bbm = mb >> 11, ss = mb & 2047;
            if (MODE == 2) {
#pragma unroll
                for (int r = 0; r < 4; ++r)
                    outf[(size_t)(mb + r) * D_DIM + n] = acc[i][j][r] + bb;
            } else if (MODE == 1) {
                ushort4 pk;
                pk.x = f2b(acc[i][j][0] + bb);
                pk.y = f2b(acc[i][j][1] + bb);
                pk.z = f2b(acc[i][j][2] + bb);
                pk.w = f2b(acc[i][j][3] + bb);
                *(ushort4*)(o1 + ((size_t)((bbm * NHEAD + hh) * HD + ee)) * S_LEN + ss) = pk;
            } else {
#pragma unroll
                for (int r = 0; r < 4; ++r) {
                    const float v = acc[i][j][r] + bb;
                    const size_t idx = ((size_t)(bbm * NHEAD + hh) * S_LEN + ss + r) * HD + ee;
                    const u16 h = f2b(v);
                    o1[idx] = h;
                    o2[idx] = f2b(v - b2f(h));
                }
            }
        }
    }
}

// ---------------------------------------------------------------------------
// Attention, ROW-OWNERSHIP restructure. Block = 512 thr (8 waves), 16 q-rows,
// loops 16 heads (R0's verified grid/occupancy: 1 block/CU, 2 waves/SIMD).
// Per head:
//   1) MFMA scores as before (wave w = cols w*256..+255, acc[16] fp32).
//   2) Stage raw fp32 scores to LDS sLds[16][2060] (129 KB; stride chosen for
//      <=2-way bank aliasing on write/read). ONE barrier.
//   3) Wave w owns rows {2w, 2w+1} (32 lanes/row, 64 vals/lane in regs):
//      mu/sigma, z-grid round 0, 5 quadrisection rounds, softmax Z -- all
//      pure in-wave shuffle reductions. ZERO barriers, ZERO serial sections,
//      identical selection arithmetic (exact integer counts, same fmaf
//      threshold formulas; count 409 +/- 1 as before).
//   4) attn bf16 written IN-PLACE into the owner's own row slot (packed
//      dword stores; no cross-wave hazard). ONE barrier.
//   5) PV bf16 MFMA reading attn rows at u16-stride 4120; pvpart combine.
//      ONE barrier. HO written bf16 hi/lo.
// Barriers/head: 3 (was ~20 + 9 serialized 16-thread finalize sections).
// ---------------------------------------------------------------------------
__global__ __launch_bounds__(512, 2)
void attn_mfma(const u16* __restrict__ Qhi, const u16* __restrict__ Qlo,
               const u16* __restrict__ Khi, const u16* __restrict__ Klo,
               const u16* __restrict__ Vt,  const float* __restrict__ temp,
               u16* __restrict__ HOhi, u16* __restrict__ HOlo,
               float* __restrict__ avg)
{
    // fp32 scores [16][2060]; attn bf16 overlaid in-place at each row's slot
    // start (row slot = 8240 B; attn row uses first 4096 B of its own slot).
    __shared__ __align__(16) float sLds[16 * 2060];   // 131,840 B
    __shared__ float pvpart[4 * 16 * 16];             // 4,096 B

    const int t = threadIdx.x, w = t >> 6, l = t & 63;
    const int lq = l & 15, quad = l >> 4;
    const int hl = l & 31, rhalf = l >> 5;            // row-ownership ids
    const int b  = blockIdx.x >> 7;
    const int q0 = (blockIdx.x & 127) << 4;
    const int myrow = 2 * w + rhalf;                  // this lane's owned row

    float avgreg[64];
#pragma unroll
    for (int i = 0; i < 64; ++i) avgreg[i] = 0.f;

#pragma unroll 1
    for (int h = 0; h < NHEAD; ++h) {
        const size_t bh = (size_t)(b * NHEAD + h) * S_LEN;
        const float tscale = 0.125f / fmaxf(temp[h], 0.1f);

        // ---- Q fragments (A-operand: lane -> row lq, k = quad*8..) --------
        const u16* qph = Qhi + (bh + q0 + lq) * HD + quad * 8;
        const u16* qpl = Qlo + (bh + q0 + lq) * HD + quad * 8;
        const bf16x8 qh0 = *(const bf16x8*)qph;
        const bf16x8 qh1 = *(const bf16x8*)(qph + 32);
        const bf16x8 ql0 = *(const bf16x8*)qpl;
        const bf16x8 ql1 = *(const bf16x8*)(qpl + 32);

        // ---- scores over this wave's 256-col chunk -------------------------
        f32x4 acc[16];
        const u16* kph = Khi + (bh + w * 256 + lq) * HD + quad * 8;
        const u16* kpl = Klo + (bh + w * 256 + lq) * HD + quad * 8;
#pragma unroll
        for (int tt = 0; tt < 16; ++tt) {
            const bf16x8 k0 = *(const bf16x8*)(kph + tt * 16 * HD);
            const bf16x8 k1 = *(const bf16x8*)(kph + tt * 16 * HD + 32);
            const bf16x8 m0 = *(const bf16x8*)(kpl + tt * 16 * HD);
            const bf16x8 m1 = *(const bf16x8*)(kpl + tt * 16 * HD + 32);
            f32x4 a = {0.f, 0.f, 0.f, 0.f};
            a = MFMA(qh0, k0, a, 0, 0, 0);
            a = MFMA(qh1, k1, a, 0, 0, 0);
            a = MFMA(qh0, m0, a, 0, 0, 0);
            a = MFMA(qh1, m1, a, 0, 0, 0);
            a = MFMA(ql0, k0, a, 0, 0, 0);
            a = MFMA(ql1, k1, a, 0, 0, 0);
            acc[tt] = a * tscale;
        }

        // ---- stage fp32 scores (prev head's PV reads ended at barD) --------
#pragma unroll
        for (int tt = 0; tt < 16; ++tt)
#pragma unroll
            for (int r = 0; r < 4; ++r)
                sLds[(quad * 4 + r) * 2060 + w * 256 + tt * 16 + lq] = acc[tt][r];
        __syncthreads();   // barB: all scores staged

        // ---- row ownership: load own row's 64 values (paired cols) ---------
        // lane (hl, rhalf): row myrow, cols {2hl + 64j, 2hl + 64j + 1}.
        float s[64];
        {
            const float* srow = sLds + (size_t)myrow * 2060 + 2 * hl;
#pragma unroll
            for (int j = 0; j < 32; ++j) {
                const float2 p = *(const float2*)(srow + 64 * j);
                s[2 * j]     = p.x;
                s[2 * j + 1] = p.y;
            }
        }

        // ---- mean / sigma (in-wave, 32-lane groups = one row) --------------
        float s1 = 0.f, s2 = 0.f;
#pragma unroll
        for (int j = 0; j < 64; ++j) { s1 += s[j]; s2 = __fmaf_rn(s[j], s[j], s2); }
#pragma unroll
        for (int off = 1; off < 32; off <<= 1) {
            s1 += __shfl_xor(s1, off, 32);
            s2 += __shfl_xor(s2, off, 32);
        }
        const float mu = s1 * (1.f / 2048.f);
        const float va = s2 * (1.f / 2048.f) - mu * mu;
        const float sg = sqrtf(fmaxf(va, 0.f));

        // ---- round 0: z-grid {0.55..1.15} + out-of-bracket fallback --------
        float lo, hi;
        {
            float th[5];
            int c[5];
#pragma unroll
            for (int i = 0; i < 5; ++i) {
                th[i] = __fmaf_rn(sg, 0.55f + 0.15f * (float)i, mu);
                c[i] = 0;
            }
#pragma unroll
            for (int j = 0; j < 64; ++j) {
                const float v = s[j];
#pragma unroll
                for (int i = 0; i < 5; ++i) c[i] += (v >= th[i]) ? 1 : 0;
            }
#pragma unroll
            for (int off = 1; off < 32; off <<= 1)
#pragma unroll
                for (int i = 0; i < 5; ++i) c[i] += __shfl_xor(c[i], off, 32);
            if (c[0] < TOPK) {
                lo = __fmaf_rn(sg, -6.f, mu);
                hi = th[0];
            } else if (c[4] >= TOPK) {
                lo = th[4];
                hi = __fmaf_rn(sg, 6.f, mu);
            } else {
                int bi = 0;
#pragma unroll
                for (int j = 1; j < 4; ++j) if (c[j] >= TOPK) bi = j;
                lo = th[bi];
                hi = th[bi + 1];
            }
        }

        // ---- 5 quadrisection refine rounds (in-wave, no barriers) ----------
#pragma unroll 1
        for (int rd = 0; rd < 5; ++rd) {
            const float w4 = __fmul_rn(__fsub_rn(hi, lo), 0.25f);
            const float t1 = __fmaf_rn(w4, 1.f, lo);
            const float t2 = __fmaf_rn(w4, 2.f, lo);
            const float t3 = __fmaf_rn(w4, 3.f, lo);
            int d0 = 0, d1 = 0, d2 = 0;
#pragma unroll
            for (int j = 0; j < 64; ++j) {
                const float v = s[j];
                d0 += (v >= t1) ? 1 : 0;
                d1 += (v >= t2) ? 1 : 0;
                d2 += (v >= t3) ? 1 : 0;
            }
#pragma unroll
            for (int off = 1; off < 32; off <<= 1) {
                d0 += __shfl_xor(d0, off, 32);
                d1 += __shfl_xor(d1, off, 32);
                d2 += __shfl_xor(d2, off, 32);
            }
            if (d2 >= TOPK)      { lo = t3; }
            else if (d1 >= TOPK) { lo = t2; hi = t3; }
            else if (d0 >= TOPK) { lo = t1; hi = t2; }
            else                 { hi = t1; }
        }

        // ---- sparse softmax (|s| small: raw exp is safe) -------------------
        const float kth = lo;
        float zp = 0.f;
#pragma unroll
        for (int j = 0; j < 64; ++j) {
            const float e = (s[j] >= kth) ? __expf(s[j]) : 0.f;
            s[j] = e;
            zp += e;
        }
#pragma unroll
        for (int off = 1; off < 32; off <<= 1) zp += __shfl_xor(zp, off, 32);
        const float zi = 1.f / zp;

        // ---- normalize, accumulate avg, write attn bf16 in-place -----------
        // Own-row slot only: no cross-wave hazard, no barrier needed before.
        {
            u16* arow = (u16*)(sLds + (size_t)myrow * 2060);
#pragma unroll
            for (int j = 0; j < 32; ++j) {
                const float a0 = s[2 * j] * zi;
                const float a1 = s[2 * j + 1] * zi;
                avgreg[2 * j]     += a0;
                avgreg[2 * j + 1] += a1;
                const unsigned pk = (unsigned)f2b(a0) | ((unsigned)f2b(a1) << 16);
                *(unsigned*)(arow + 2 * hl + 64 * j) = pk;
            }
        }
        __syncthreads();   // barC: attn rows complete

        // ---- PV: wave w -> e-tile (w&3), j-half (w>>2); 32 K-steps ---------
        const int et = w & 3, jh = w >> 2;
        const u16* vb = Vt + ((size_t)(b * NHEAD + h) * HD + et * 16 + lq) * S_LEN
                        + jh * 1024 + quad * 8;
        const u16* ab = (const u16*)sLds + (size_t)lq * 4120 + jh * 1024 + quad * 8;
        f32x4 pv = {0.f, 0.f, 0.f, 0.f};
#pragma unroll 8
        for (int st = 0; st < 32; ++st) {
            const bf16x8 af = *(const bf16x8*)(ab + st * 32);
            const bf16x8 vf = *(const bf16x8*)(vb + st * 32);
            pv = MFMA(af, vf, pv, 0, 0, 0);
        }
        if (w >= 4) {
#pragma unroll
            for (int r = 0; r < 4; ++r)
                pvpart[(et * 16 + quad * 4 + r) * 16 + lq] = pv[r];
        }
        __syncthreads();   // barD: pvpart ready AND all attn/PV reads done
        if (w < 4) {
#pragma unroll
            for (int r = 0; r < 4; ++r) {
                const float v = pv[r] + pvpart[(et * 16 + quad * 4 + r) * 16 + lq];
                const size_t idx =
                    ((size_t)(b * S_LEN + q0 + quad * 4 + r)) * D_DIM + h * HD + et * 16 + lq;
                const u16 hv = f2b(v);
                HOhi[idx] = hv;
                HOlo[idx] = f2b(v - b2f(hv));
            }
        }
    } // heads

    // ---- avg_attention = mean over heads (own row, paired cols) ------------
    float* avrow = avg + ((size_t)(b * S_LEN + q0 + myrow)) * S_LEN + 2 * hl;
#pragma unroll
    for (int j = 0; j < 32; ++j) {
        float2 o;
        o.x = avgreg[2 * j]     * (1.f / NHEAD);
        o.y = avgreg[2 * j + 1] * (1.f / NHEAD);
        *(float2*)(avrow + 64 * j) = o;
    }
}

// ---------------------------------------------------------------------------
extern "C" void kernel_launch(void* const* d_in, const int* in_sizes, int n_in,
                              void* d_out, int out_size, void* d_ws, size_t ws_size,
                              hipStream_t stream)
{
    const float* x    = (const float*)d_in[0];
    const float* Wq   = (const float*)d_in[1];
    const float* bq   = (const float*)d_in[2];
    const float* Wk   = (const float*)d_in[3];
    const float* bk   = (const float*)d_in[4];
    const float* Wv   = (const float*)d_in[5];
    const float* bv   = (const float*)d_in[6];
    const float* Wo   = (const float*)d_in[7];
    const float* bo   = (const float*)d_in[8];
    const float* temp = (const float*)d_in[9];
    float* out = (float*)d_out;

    const int B = in_sizes[0] / (S_LEN * D_DIM);   // 2
    const int M = B * S_LEN;                       // 4096
    const size_t NQ = (size_t)M * D_DIM;
    const size_t NW = (size_t)D_DIM * D_DIM;

    u16* Qhi = (u16*)d_ws;
    u16* Qlo = Qhi + NQ;
    u16* Khi = Qlo + NQ;
    u16* Klo = Khi + NQ;
    u16* Vt  = Klo + NQ;
    u16* Xhi = Vt  + NQ;   // reused as HOhi after QKV GEMMs
    u16* Xlo = Xhi + NQ;   // reused as HOlo
    u16* Wqh = Xlo + NQ;
    u16* Wql = Wqh + NW;
    u16* Wkh = Wql + NW;
    u16* Wkl = Wkh + NW;
    u16* Wvh = Wkl + NW;
    u16* Wvl = Wvh + NW;
    u16* Woh = Wvl + NW;
    u16* Wol = Woh + NW;
    float* avg = out + NQ;

    const int n4x = (int)(NQ / 4), n4w = (int)(NW / 4);
    split_f32<<<(n4x + 255) / 256, 256, 0, stream>>>(x, Xhi, Xlo, n4x);
    split4_f32<<<dim3((n4w + 255) / 256, 4), 256, 0, stream>>>(
        Wq, Wk, Wv, Wo, Wqh, Wql, Wkh, Wkl, Wvh, Wvl, Woh, Wol, n4w);

    dim3 gg(D_DIM / 128, M / 128, 1);
    proj_mfma<0><<<gg, 512, 0, stream>>>(Xhi, Xlo, Wqh, Wql, bq, nullptr, Qhi, Qlo);
    proj_mfma<0><<<gg, 512, 0, stream>>>(Xhi, Xlo, Wkh, Wkl, bk, nullptr, Khi, Klo);
    proj_mfma<1><<<gg, 512, 0, stream>>>(Xhi, Xlo, Wvh, Wvl, bv, nullptr, Vt, nullptr);

    attn_mfma<<<dim3(M / 16), 512, 0, stream>>>(Qhi, Qlo, Khi, Klo, Vt, temp,
                                                Xhi, Xlo, avg);

    proj_mfma<2><<<gg, 512, 0, stream>>>(Xhi, Xlo, Woh, Wol, bo, out, nullptr, nullptr);
}